// Round 3
// baseline (581.047 us; speedup 1.0000x reference)
//
#include <hip/hip_runtime.h>

typedef unsigned int u32;
typedef float __attribute__((ext_vector_type(4))) fvec4;  // native vector for nontemporal builtin

// Order-preserving float<->uint mapping for integer atomicMin/Max.
__device__ __forceinline__ u32 f2ord(float f) {
    u32 b = __float_as_uint(f);
    return (b & 0x80000000u) ? ~b : (b | 0x80000000u);
}
__device__ __forceinline__ float ord2f(u32 k) {
    u32 b = (k & 0x80000000u) ? (k ^ 0x80000000u) : ~k;
    return __uint_as_float(b);
}

// ---------------- Kernel A: global min/max reduction ----------------
__global__ __launch_bounds__(256) void minmax_kernel(const float4* __restrict__ x, int n4,
                                                     u32* __restrict__ ws) {
    float mn = INFINITY, mx = -INFINITY;
    int stride = gridDim.x * blockDim.x;
    #pragma unroll 4
    for (int i = blockIdx.x * blockDim.x + threadIdx.x; i < n4; i += stride) {
        float4 v = x[i];
        mn = fminf(mn, fminf(fminf(v.x, v.y), fminf(v.z, v.w)));
        mx = fmaxf(mx, fmaxf(fmaxf(v.x, v.y), fmaxf(v.z, v.w)));
    }
    // wave(64) shuffle reduction
    #pragma unroll
    for (int off = 32; off > 0; off >>= 1) {
        mn = fminf(mn, __shfl_down(mn, off, 64));
        mx = fmaxf(mx, __shfl_down(mx, off, 64));
    }
    __shared__ float smn[4], smx[4];
    int wave = threadIdx.x >> 6;
    int lane = threadIdx.x & 63;
    if (lane == 0) { smn[wave] = mn; smx[wave] = mx; }
    __syncthreads();
    if (threadIdx.x == 0) {
        #pragma unroll
        for (int w = 1; w < 4; ++w) { mn = fminf(mn, smn[w]); mx = fmaxf(mx, smx[w]); }
        atomicMin(&ws[0], f2ord(mn));
        atomicMax(&ws[1], f2ord(mx));
    }
}

// ---------------- Kernel B: spline apply (uniform-knot closed form) ----------------
// knots = linspace(0,1,32) -> knot[b] == b/31 (to ~1 ulp). So:
//   u = (x - mn) * (31 / (mx - mn + 1e-6));  b = min((int)u, 30);  t = u - b
//   out = cp[b] + t * (cp[b+1] - cp[b])
// xn is always in [0,1) (mn/mx are exact attained extrema), so no range mask.
// cp/dcp table is gathered via __shfl (ds_bpermute: conflict-free crossbar).
__global__ __launch_bounds__(256) void apply_kernel(const float4* __restrict__ x,
                                                    const float* __restrict__ cp,
                                                    const u32* __restrict__ ws,
                                                    float4* __restrict__ out, int n4) {
    int lane = threadIdx.x & 63;
    int tidx = lane & 31;
    float cpl = cp[tidx];                                  // lane i holds cp[i&31]
    float dpl = (tidx < 31) ? (cp[tidx + 1] - cpl) : 0.0f; // slope numerator; b<=30 so lane31 unused

    float mn = ord2f(ws[0]);
    float mx = ord2f(ws[1]);
    float scale31 = 31.0f / (mx - mn + 1e-6f);

    int stride = gridDim.x * blockDim.x;
    for (int i = blockIdx.x * blockDim.x + threadIdx.x; i < n4; i += stride) {
        float4 v = x[i];
        fvec4 r;
        float* vp = (float*)&v;
        float* rp = (float*)&r;
        #pragma unroll
        for (int c = 0; c < 4; ++c) {
            float u = (vp[c] - mn) * scale31;   // u in [0, 31)
            int b = (int)u;                     // trunc; u >= 0 by construction
            b = b > 30 ? 30 : b;
            float t = u - (float)b;
            float a = __shfl(cpl, b, 64);
            float d = __shfl(dpl, b, 64);
            rp[c] = fmaf(t, d, a);
        }
        __builtin_nontemporal_store(r, (fvec4*)&out[i]);  // don't let out evict x from L3
    }
}

extern "C" void kernel_launch(void* const* d_in, const int* in_sizes, int n_in,
                              void* d_out, int out_size, void* d_ws, size_t ws_size,
                              hipStream_t stream) {
    const float* x  = (const float*)d_in[0];
    const float* cp = (const float*)d_in[1];
    float* out = (float*)d_out;
    u32* ws = (u32*)d_ws;

    int n  = in_sizes[0];      // 64 * 1048576, divisible by 4
    int n4 = n / 4;

    // init reduction cells: min key = 0xFFFFFFFF, max key = 0x00000000
    (void)hipMemsetAsync(ws, 0xFF, 4, stream);
    (void)hipMemsetAsync(ws + 1, 0x00, 4, stream);

    minmax_kernel<<<8192, 256, 0, stream>>>((const float4*)x, n4, ws);
    apply_kernel <<<8192, 256, 0, stream>>>((const float4*)x, cp, ws,
                                            (float4*)out, n4);
}